// Round 12
// baseline (294.467 us; speedup 1.0000x reference)
//
#include <hip/hip_runtime.h>
#include <hip/hip_bf16.h>

#define HH 256
#define WW 256
#define HW (HH * WW)

typedef float f32x4 __attribute__((ext_vector_type(4)));
typedef float v2f __attribute__((ext_vector_type(2)));
typedef short bf16x8 __attribute__((ext_vector_type(8)));

__device__ __forceinline__ unsigned short f2bf(float f) {
    unsigned u = __builtin_bit_cast(unsigned, f);
    return (unsigned short)((u + 0x7FFFu + ((u >> 16) & 1u)) >> 16);
}
__device__ __forceinline__ v2f bfpair(unsigned u) {
    return (v2f){ __builtin_bit_cast(float, u << 16),
                  __builtin_bit_cast(float, u & 0xFFFF0000u) };
}
// RNE pack of two f32 -> packed bf16x2 (lo = first arg). Single v_cvt_pk_bf16_f32.
// (__hip_bfloat162 is not trivially copyable on this ROCm -> memcpy the bits.)
__device__ __forceinline__ unsigned pk_bf16(float lo, float hi) {
    __hip_bfloat162 h = __float22bfloat162_rn(make_float2(lo, hi));
    unsigned r;
    __builtin_memcpy(&r, &h, sizeof(r));
    return r;
}

// x[b][c][h][w] fp32 -> xT[b][h][w][c] bf16. 4 threads/pixel x 16ch, 2048 blocks.
__global__ void xt_kernel(const float* __restrict__ x, unsigned short* __restrict__ xT) {
    const int gid = blockIdx.x * 256 + threadIdx.x;       // 0..524287
    const int pix = gid >> 2;                             // 0..131071
    const int c16 = gid & 3;
    const float* xp = x + (size_t)(pix >> 16) * 64 * HW + (pix & 65535) + (size_t)(c16 * 16) * HW;
    unsigned short* op = xT + (size_t)pix * 64 + c16 * 16;
    unsigned q[8];
#pragma unroll
    for (int j = 0; j < 8; ++j) {
        float a = xp[(size_t)(2 * j) * HW];
        float b = xp[(size_t)(2 * j + 1) * HW];
        q[j] = pk_bf16(a, b);
    }
    *(uint4*)(op) = make_uint4(q[0], q[1], q[2], q[3]);
    *(uint4*)(op + 8) = make_uint4(q[4], q[5], q[6], q[7]);
}

// Weight prep:
//  WcombB[s][o][c] bf16 (s=i*9+t): sum_c2 Wfuse[o][i*64+c2] * Wd[i][c2][c][t]
//  WoffR[t][n(64 pad)][c] bf16 from Woff[n][c][t]
__global__ void wprep_kernel(const float* __restrict__ Wd,
                             const float* __restrict__ Wfuse,
                             const float* __restrict__ Woff,
                             unsigned short* __restrict__ WcombB,
                             unsigned short* __restrict__ WoffR) {
    int idx = blockIdx.x * 256 + threadIdx.x;
    if (idx < 27 * 64 * 64) {
        int c = idx & 63, o = (idx >> 6) & 63, s = idx >> 12;
        int i = s / 9, t = s - i * 9;
        const float* wf = Wfuse + o * 192 + i * 64;
        const float* wd = Wd + ((size_t)(i * 64) * 64 + c) * 9 + t;
        float acc = 0.f;
        for (int c2 = 0; c2 < 64; ++c2)
            acc = fmaf(wf[c2], wd[(size_t)c2 * 576], acc);
        WcombB[idx] = f2bf(acc);          // (s*64+o)*64 + c
    } else {
        int j = idx - 27 * 64 * 64;
        if (j < 9 * 64 * 64) {
            int c = j & 63, n = (j >> 6) & 63, t = j >> 12;
            float v = (n < 54) ? Woff[(size_t)(n * 64 + c) * 9 + t] : 0.f;
            WoffR[j] = f2bf(v);           // (t*64+n)*64 + c
        }
    }
}

// Block = 4 waves, one 64-pixel row segment. R11 structure (monolithic produce,
// 4 threads/pixel x 16ch, offL 54 rows, Sb pitch 70, 5 blocks/CU).
// SINGLE delta this round: tap-load line grouping. Previously each thread loaded
// bytes (c16*32 + {0,16}) of the 128B pixel record -> within one instruction a
// pixel's 4 lanes straddle BOTH 64B lines (32 lines/instr/wave; 8 instrs = 256
// TA line-transactions per slice-wave, ~42% of kernel cycles in the L1/TA pipe,
// paid even on L1 hits). Now each thread loads (c16*16 + {0, 64B}): all 4 lanes
// of a pixel hit the SAME 64B line per instruction -> 16 lines/instr -> 128
// transactions (halved). Thread owns channels [c16*8,+8) u [32+c16*8,+8);
// Sb writes follow; each (p,c) still written once, identical math -> bit-identical.
// Probed-null ledger: occupancy 41->47% (R9): 0. Sb bank pitch 66->70 (R11): 0,
// SQ_LDS_BANK_CONFLICT invariant (red herring). VALU halving (R7): -6us only.
// (Produce-interior restructures remain forbidden: R1/R3/R4/R8 corrupt ~0.3.)
__launch_bounds__(256, 5)
__global__ void mspadc_main(const unsigned short* __restrict__ xT,
                            const unsigned short* __restrict__ WoffR,
                            const float* __restrict__ boff,
                            const unsigned short* __restrict__ WcombB,
                            float* __restrict__ out) {
    __shared__ float offL[54 * 65];                          // [n<54][p] pitch 65
    __shared__ __align__(16) unsigned short Sb[2][64 * 70];  // [p][c] pitch 70

    const int tid = threadIdx.x, lane = tid & 63, wv = tid >> 6;
    const int l15 = lane & 15, lq = lane >> 4;

    const unsigned u = blockIdx.x;
    const int xcd = u & 7, v = u >> 3;                    // XCD-band swizzle
    const int row = xcd * 64 + (v >> 2);                  // 0..511
    const int b = row >> 8, h = row & 255;
    const int w0 = (v & 3) << 6;

    const unsigned short* xTb = xT + (size_t)b * HW * 64;

    f32x4 acc[4];
#pragma unroll
    for (int nt = 0; nt < 4; ++nt) acc[nt] = (f32x4){0.f, 0.f, 0.f, 0.f};

    // ---------------- Phase 1: offset conv GEMM ----------------
#pragma unroll
    for (int t = 0; t < 9; ++t) {
        const int hh = h + t / 3 - 1;
        const bool hv = (hh >= 0) && (hh < HH);
#pragma unroll
        for (int kk = 0; kk < 2; ++kk) {
            bf16x8 a = *(const bf16x8*)(WoffR + (size_t)((t * 64 + 16 * wv + l15) * 64 + kk * 32 + lq * 8));
#pragma unroll
            for (int nt = 0; nt < 4; ++nt) {
                const int ww = w0 + nt * 16 + l15 + (t % 3) - 1;
                bf16x8 bf_ = {0, 0, 0, 0, 0, 0, 0, 0};
                if (hv && ww >= 0 && ww < WW)
                    bf_ = *(const bf16x8*)(xTb + (size_t)(hh * WW + ww) * 64 + kk * 32 + lq * 8);
                acc[nt] = __builtin_amdgcn_mfma_f32_16x16x32_bf16(a, bf_, acc[nt], 0, 0, 0);
            }
        }
    }
#pragma unroll
    for (int r = 0; r < 4; ++r) {
        const int nch = 16 * wv + lq * 4 + r;
        if (nch < 54) {                      // rows >=54 are never read
            const float bo = boff[nch];
#pragma unroll
            for (int nt = 0; nt < 4; ++nt)
                offL[nch * 65 + nt * 16 + l15] = acc[nt][r] + bo;
        }
    }
    __syncthreads();

#pragma unroll
    for (int nt = 0; nt < 4; ++nt) acc[nt] = (f32x4){0.f, 0.f, 0.f, 0.f};

    // ---------------- Phase 2: gather + main GEMM ----------------
    const int c16 = tid & 3;       // channel group: [c16*8,+8) and [32+c16*8,+8)
    const int px  = tid >> 2;      // pixel 0..63 (one per thread)

    auto produce = [&](int s, int buf) {
        const int i = s / 9, t = s - i * 9;
        const int d = 1 << i;
        const int p = px;
        const float dy = offL[(i * 18 + 2 * t) * 65 + p];
        const float dx = offL[(i * 18 + 2 * t + 1) * 65 + p];
        const float ys = (float)(h + (t / 3 - 1) * d) + dy;
        const float xs = (float)(w0 + p + (t % 3 - 1) * d) + dx;
        const float y0f = floorf(ys), x0f = floorf(xs);
        const float wy1 = ys - y0f, wx1 = xs - x0f;
        const float wy0 = 1.f - wy1, wx0 = 1.f - wx1;
        const float vy0 = (y0f >= 0.f && y0f <= 255.f) ? 1.f : 0.f;
        const float vy1 = (y0f >= -1.f && y0f <= 254.f) ? 1.f : 0.f;
        const float vx0 = (x0f >= 0.f && x0f <= 255.f) ? 1.f : 0.f;
        const float vx1 = (x0f >= -1.f && x0f <= 254.f) ? 1.f : 0.f;
        const float c00 = wy0 * wx0 * vy0 * vx0;
        const float c01 = wy0 * wx1 * vy0 * vx1;
        const float c10 = wy1 * wx0 * vy1 * vx0;
        const float c11 = wy1 * wx1 * vy1 * vx1;
        const int y0 = (int)fminf(fmaxf(y0f, 0.f), 255.f);
        const int x0 = (int)fminf(fmaxf(x0f, 0.f), 255.f);
        const int oxs = (((int)fminf(fmaxf(x0f + 1.f, 0.f), 255.f)) - x0) * 64;
        const int oyW = (((int)fminf(fmaxf(y0f + 1.f, 0.f), 255.f)) - y0) * WW * 64;
        const unsigned short* pc = xTb + (size_t)(y0 * WW + x0) * 64 + c16 * 8;
        const uint4 u00a = *(const uint4*)(pc);            // line 0 of record
        const uint4 u00b = *(const uint4*)(pc + 32);       // line 1 (+64B)
        const uint4 u01a = *(const uint4*)(pc + oxs);
        const uint4 u01b = *(const uint4*)(pc + oxs + 32);
        const uint4 u10a = *(const uint4*)(pc + oyW);
        const uint4 u10b = *(const uint4*)(pc + oyW + 32);
        const uint4 u11a = *(const uint4*)(pc + oyW + oxs);
        const uint4 u11b = *(const uint4*)(pc + oyW + oxs + 32);
        const unsigned a00[8] = {u00a.x, u00a.y, u00a.z, u00a.w, u00b.x, u00b.y, u00b.z, u00b.w};
        const unsigned a01[8] = {u01a.x, u01a.y, u01a.z, u01a.w, u01b.x, u01b.y, u01b.z, u01b.w};
        const unsigned a10[8] = {u10a.x, u10a.y, u10a.z, u10a.w, u10b.x, u10b.y, u10b.z, u10b.w};
        const unsigned a11[8] = {u11a.x, u11a.y, u11a.z, u11a.w, u11b.x, u11b.y, u11b.z, u11b.w};
        const v2f c00v = {c00, c00}, c01v = {c01, c01};
        const v2f c10v = {c10, c10}, c11v = {c11, c11};
        unsigned q[8];
#pragma unroll
        for (int j = 0; j < 8; ++j) {
            v2f s2 = bfpair(a00[j]) * c00v;
            s2 = __builtin_elementwise_fma(bfpair(a01[j]), c01v, s2);
            s2 = __builtin_elementwise_fma(bfpair(a10[j]), c10v, s2);
            s2 = __builtin_elementwise_fma(bfpair(a11[j]), c11v, s2);
            q[j] = pk_bf16(s2.x, s2.y);
        }
        *(uint4*)(&Sb[buf][p * 70 + c16 * 8]) = make_uint4(q[0], q[1], q[2], q[3]);
        *(uint4*)(&Sb[buf][p * 70 + 32 + c16 * 8]) = make_uint4(q[4], q[5], q[6], q[7]);
    };

    auto consume = [&](int s, int buf) {
#pragma unroll
        for (int kk = 0; kk < 2; ++kk) {
            bf16x8 a = *(const bf16x8*)(WcombB + (size_t)((s * 64 + 16 * wv + l15) * 64 + kk * 32 + lq * 8));
#pragma unroll
            for (int nt = 0; nt < 4; ++nt) {
                bf16x8 bb = *(const bf16x8*)(&Sb[buf][(nt * 16 + l15) * 70 + kk * 32 + lq * 8]);
                acc[nt] = __builtin_amdgcn_mfma_f32_16x16x32_bf16(a, bb, acc[nt], 0, 0, 0);
            }
        }
    };

    produce(0, 0);
    __syncthreads();
    for (int s = 0; s < 27; ++s) {
        if (s < 26) produce(s + 1, (s + 1) & 1);
        consume(s, s & 1);
        __syncthreads();
    }

    // ---------------- Epilogue ----------------
    float* ob = out + (size_t)b * 64 * HW + h * WW + w0;
#pragma unroll
    for (int nt = 0; nt < 4; ++nt)
#pragma unroll
        for (int r = 0; r < 4; ++r) {
            const int o = 16 * wv + lq * 4 + r;
            ob[(size_t)o * HW + nt * 16 + l15] = acc[nt][r];
        }
}

extern "C" void kernel_launch(void* const* d_in, const int* in_sizes, int n_in,
                              void* d_out, int out_size, void* d_ws, size_t ws_size,
                              hipStream_t stream) {
    const float* x     = (const float*)d_in[0];
    const float* Woff  = (const float*)d_in[1];
    const float* boff  = (const float*)d_in[2];
    const float* Wd    = (const float*)d_in[3];
    const float* Wfuse = (const float*)d_in[4];
    float* out = (float*)d_out;

    unsigned short* WcombB = (unsigned short*)d_ws;        // 27*64*64*2   = 221184 B
    unsigned short* WoffR  = WcombB + 27 * 64 * 64;        // 9*64*64*2    =  73728 B
    unsigned short* xT     = WoffR + 9 * 64 * 64;          // 2*HW*64*2    = 16.78 MB

    xt_kernel<<<2048, 256, 0, stream>>>(x, xT);
    wprep_kernel<<<576, 256, 0, stream>>>(Wd, Wfuse, Woff, WcombB, WoffR);
    mspadc_main<<<2048, 256, 0, stream>>>(xT, WoffR, boff, WcombB, out);
}

// Round 13
// 292.282 us; speedup vs baseline: 1.0075x; 1.0075x over previous
//
#include <hip/hip_runtime.h>
#include <hip/hip_bf16.h>

#define HH 256
#define WW 256
#define HW (HH * WW)

typedef float f32x4 __attribute__((ext_vector_type(4)));
typedef float v2f __attribute__((ext_vector_type(2)));
typedef short bf16x8 __attribute__((ext_vector_type(8)));

__device__ __forceinline__ unsigned short f2bf(float f) {
    unsigned u = __builtin_bit_cast(unsigned, f);
    return (unsigned short)((u + 0x7FFFu + ((u >> 16) & 1u)) >> 16);
}
__device__ __forceinline__ v2f bfpair(unsigned u) {
    return (v2f){ __builtin_bit_cast(float, u << 16),
                  __builtin_bit_cast(float, u & 0xFFFF0000u) };
}
// RNE pack of two f32 -> packed bf16x2 (lo = first arg). Single v_cvt_pk_bf16_f32.
// (__hip_bfloat162 is not trivially copyable on this ROCm -> memcpy the bits.)
__device__ __forceinline__ unsigned pk_bf16(float lo, float hi) {
    __hip_bfloat162 h = __float22bfloat162_rn(make_float2(lo, hi));
    unsigned r;
    __builtin_memcpy(&r, &h, sizeof(r));
    return r;
}

// MERGED prep kernel (R13 delta): blocks [0,2048) run the former xt_kernel body,
// blocks [2048,2624) run the former wprep_kernel body — both byte-identical to
// their R12 versions. Rationale: wprep alone had 2.25 blocks/CU (9 waves/CU) with
// a 64-deep dependent-FMA chain + stride-2304B Wd loads = latency-starved; xt
// alone is memory-bound. Co-residency overlaps them and saves one launch.
// No consumer (mspadc) starts until the whole kernel ends -> same ordering.
__global__ void prep_kernel(const float* __restrict__ x, unsigned short* __restrict__ xT,
                            const float* __restrict__ Wd,
                            const float* __restrict__ Wfuse,
                            const float* __restrict__ Woff,
                            unsigned short* __restrict__ WcombB,
                            unsigned short* __restrict__ WoffR) {
    if (blockIdx.x < 2048) {
        // ---- xT transpose: x[b][c][h][w] fp32 -> xT[b][h][w][c] bf16 ----
        const int gid = blockIdx.x * 256 + threadIdx.x;       // 0..524287
        const int pix = gid >> 2;                             // 0..131071
        const int c16 = gid & 3;
        const float* xp = x + (size_t)(pix >> 16) * 64 * HW + (pix & 65535) + (size_t)(c16 * 16) * HW;
        unsigned short* op = xT + (size_t)pix * 64 + c16 * 16;
        unsigned q[8];
#pragma unroll
        for (int j = 0; j < 8; ++j) {
            float a = xp[(size_t)(2 * j) * HW];
            float b = xp[(size_t)(2 * j + 1) * HW];
            q[j] = pk_bf16(a, b);
        }
        *(uint4*)(op) = make_uint4(q[0], q[1], q[2], q[3]);
        *(uint4*)(op + 8) = make_uint4(q[4], q[5], q[6], q[7]);
    } else {
        // ---- weight prep ----
        //  WcombB[s][o][c] bf16 (s=i*9+t): sum_c2 Wfuse[o][i*64+c2] * Wd[i][c2][c][t]
        //  WoffR[t][n(64 pad)][c] bf16 from Woff[n][c][t]
        int idx = (blockIdx.x - 2048) * 256 + threadIdx.x;
        if (idx < 27 * 64 * 64) {
            int c = idx & 63, o = (idx >> 6) & 63, s = idx >> 12;
            int i = s / 9, t = s - i * 9;
            const float* wf = Wfuse + o * 192 + i * 64;
            const float* wd = Wd + ((size_t)(i * 64) * 64 + c) * 9 + t;
            float acc = 0.f;
            for (int c2 = 0; c2 < 64; ++c2)
                acc = fmaf(wf[c2], wd[(size_t)c2 * 576], acc);
            WcombB[idx] = f2bf(acc);          // (s*64+o)*64 + c
        } else {
            int j = idx - 27 * 64 * 64;
            if (j < 9 * 64 * 64) {
                int c = j & 63, n = (j >> 6) & 63, t = j >> 12;
                float v = (n < 54) ? Woff[(size_t)(n * 64 + c) * 9 + t] : 0.f;
                WoffR[j] = f2bf(v);           // (t*64+n)*64 + c
            }
        }
    }
}

// Block = 4 waves, one 64-pixel row segment. UNCHANGED from R12 (verified 220.9us,
// absmax 0.015625). Probe ledger — all resource levers null: VALU halved (R7,
// -6us), occupancy 41->47% (R9, 0), Sb bank pitch (R11, 0), TA line grouping
// (R12, 0). Remaining ~50% stall = per-slice gather->combine->barrier latency
// chain; the only fix class (prefetch across consume / produce split) corrupts
// output on this toolchain (R1/R3/R4/R8, 4/4 fails ~0.3 absmax, build-varying).
// This kernel is at its structural floor — DO NOT restructure produce/consume.
__launch_bounds__(256, 5)
__global__ void mspadc_main(const unsigned short* __restrict__ xT,
                            const unsigned short* __restrict__ WoffR,
                            const float* __restrict__ boff,
                            const unsigned short* __restrict__ WcombB,
                            float* __restrict__ out) {
    __shared__ float offL[54 * 65];                          // [n<54][p] pitch 65
    __shared__ __align__(16) unsigned short Sb[2][64 * 70];  // [p][c] pitch 70

    const int tid = threadIdx.x, lane = tid & 63, wv = tid >> 6;
    const int l15 = lane & 15, lq = lane >> 4;

    const unsigned u = blockIdx.x;
    const int xcd = u & 7, v = u >> 3;                    // XCD-band swizzle
    const int row = xcd * 64 + (v >> 2);                  // 0..511
    const int b = row >> 8, h = row & 255;
    const int w0 = (v & 3) << 6;

    const unsigned short* xTb = xT + (size_t)b * HW * 64;

    f32x4 acc[4];
#pragma unroll
    for (int nt = 0; nt < 4; ++nt) acc[nt] = (f32x4){0.f, 0.f, 0.f, 0.f};

    // ---------------- Phase 1: offset conv GEMM ----------------
#pragma unroll
    for (int t = 0; t < 9; ++t) {
        const int hh = h + t / 3 - 1;
        const bool hv = (hh >= 0) && (hh < HH);
#pragma unroll
        for (int kk = 0; kk < 2; ++kk) {
            bf16x8 a = *(const bf16x8*)(WoffR + (size_t)((t * 64 + 16 * wv + l15) * 64 + kk * 32 + lq * 8));
#pragma unroll
            for (int nt = 0; nt < 4; ++nt) {
                const int ww = w0 + nt * 16 + l15 + (t % 3) - 1;
                bf16x8 bf_ = {0, 0, 0, 0, 0, 0, 0, 0};
                if (hv && ww >= 0 && ww < WW)
                    bf_ = *(const bf16x8*)(xTb + (size_t)(hh * WW + ww) * 64 + kk * 32 + lq * 8);
                acc[nt] = __builtin_amdgcn_mfma_f32_16x16x32_bf16(a, bf_, acc[nt], 0, 0, 0);
            }
        }
    }
#pragma unroll
    for (int r = 0; r < 4; ++r) {
        const int nch = 16 * wv + lq * 4 + r;
        if (nch < 54) {                      // rows >=54 are never read
            const float bo = boff[nch];
#pragma unroll
            for (int nt = 0; nt < 4; ++nt)
                offL[nch * 65 + nt * 16 + l15] = acc[nt][r] + bo;
        }
    }
    __syncthreads();

#pragma unroll
    for (int nt = 0; nt < 4; ++nt) acc[nt] = (f32x4){0.f, 0.f, 0.f, 0.f};

    // ---------------- Phase 2: gather + main GEMM ----------------
    const int c16 = tid & 3;       // channel group: [c16*8,+8) and [32+c16*8,+8)
    const int px  = tid >> 2;      // pixel 0..63 (one per thread)

    auto produce = [&](int s, int buf) {
        const int i = s / 9, t = s - i * 9;
        const int d = 1 << i;
        const int p = px;
        const float dy = offL[(i * 18 + 2 * t) * 65 + p];
        const float dx = offL[(i * 18 + 2 * t + 1) * 65 + p];
        const float ys = (float)(h + (t / 3 - 1) * d) + dy;
        const float xs = (float)(w0 + p + (t % 3 - 1) * d) + dx;
        const float y0f = floorf(ys), x0f = floorf(xs);
        const float wy1 = ys - y0f, wx1 = xs - x0f;
        const float wy0 = 1.f - wy1, wx0 = 1.f - wx1;
        const float vy0 = (y0f >= 0.f && y0f <= 255.f) ? 1.f : 0.f;
        const float vy1 = (y0f >= -1.f && y0f <= 254.f) ? 1.f : 0.f;
        const float vx0 = (x0f >= 0.f && x0f <= 255.f) ? 1.f : 0.f;
        const float vx1 = (x0f >= -1.f && x0f <= 254.f) ? 1.f : 0.f;
        const float c00 = wy0 * wx0 * vy0 * vx0;
        const float c01 = wy0 * wx1 * vy0 * vx1;
        const float c10 = wy1 * wx0 * vy1 * vx0;
        const float c11 = wy1 * wx1 * vy1 * vx1;
        const int y0 = (int)fminf(fmaxf(y0f, 0.f), 255.f);
        const int x0 = (int)fminf(fmaxf(x0f, 0.f), 255.f);
        const int oxs = (((int)fminf(fmaxf(x0f + 1.f, 0.f), 255.f)) - x0) * 64;
        const int oyW = (((int)fminf(fmaxf(y0f + 1.f, 0.f), 255.f)) - y0) * WW * 64;
        const unsigned short* pc = xTb + (size_t)(y0 * WW + x0) * 64 + c16 * 8;
        const uint4 u00a = *(const uint4*)(pc);            // line 0 of record
        const uint4 u00b = *(const uint4*)(pc + 32);       // line 1 (+64B)
        const uint4 u01a = *(const uint4*)(pc + oxs);
        const uint4 u01b = *(const uint4*)(pc + oxs + 32);
        const uint4 u10a = *(const uint4*)(pc + oyW);
        const uint4 u10b = *(const uint4*)(pc + oyW + 32);
        const uint4 u11a = *(const uint4*)(pc + oyW + oxs);
        const uint4 u11b = *(const uint4*)(pc + oyW + oxs + 32);
        const unsigned a00[8] = {u00a.x, u00a.y, u00a.z, u00a.w, u00b.x, u00b.y, u00b.z, u00b.w};
        const unsigned a01[8] = {u01a.x, u01a.y, u01a.z, u01a.w, u01b.x, u01b.y, u01b.z, u01b.w};
        const unsigned a10[8] = {u10a.x, u10a.y, u10a.z, u10a.w, u10b.x, u10b.y, u10b.z, u10b.w};
        const unsigned a11[8] = {u11a.x, u11a.y, u11a.z, u11a.w, u11b.x, u11b.y, u11b.z, u11b.w};
        const v2f c00v = {c00, c00}, c01v = {c01, c01};
        const v2f c10v = {c10, c10}, c11v = {c11, c11};
        unsigned q[8];
#pragma unroll
        for (int j = 0; j < 8; ++j) {
            v2f s2 = bfpair(a00[j]) * c00v;
            s2 = __builtin_elementwise_fma(bfpair(a01[j]), c01v, s2);
            s2 = __builtin_elementwise_fma(bfpair(a10[j]), c10v, s2);
            s2 = __builtin_elementwise_fma(bfpair(a11[j]), c11v, s2);
            q[j] = pk_bf16(s2.x, s2.y);
        }
        *(uint4*)(&Sb[buf][p * 70 + c16 * 8]) = make_uint4(q[0], q[1], q[2], q[3]);
        *(uint4*)(&Sb[buf][p * 70 + 32 + c16 * 8]) = make_uint4(q[4], q[5], q[6], q[7]);
    };

    auto consume = [&](int s, int buf) {
#pragma unroll
        for (int kk = 0; kk < 2; ++kk) {
            bf16x8 a = *(const bf16x8*)(WcombB + (size_t)((s * 64 + 16 * wv + l15) * 64 + kk * 32 + lq * 8));
#pragma unroll
            for (int nt = 0; nt < 4; ++nt) {
                bf16x8 bb = *(const bf16x8*)(&Sb[buf][(nt * 16 + l15) * 70 + kk * 32 + lq * 8]);
                acc[nt] = __builtin_amdgcn_mfma_f32_16x16x32_bf16(a, bb, acc[nt], 0, 0, 0);
            }
        }
    };

    produce(0, 0);
    __syncthreads();
    for (int s = 0; s < 27; ++s) {
        if (s < 26) produce(s + 1, (s + 1) & 1);
        consume(s, s & 1);
        __syncthreads();
    }

    // ---------------- Epilogue ----------------
    float* ob = out + (size_t)b * 64 * HW + h * WW + w0;
#pragma unroll
    for (int nt = 0; nt < 4; ++nt)
#pragma unroll
        for (int r = 0; r < 4; ++r) {
            const int o = 16 * wv + lq * 4 + r;
            ob[(size_t)o * HW + nt * 16 + l15] = acc[nt][r];
        }
}

extern "C" void kernel_launch(void* const* d_in, const int* in_sizes, int n_in,
                              void* d_out, int out_size, void* d_ws, size_t ws_size,
                              hipStream_t stream) {
    const float* x     = (const float*)d_in[0];
    const float* Woff  = (const float*)d_in[1];
    const float* boff  = (const float*)d_in[2];
    const float* Wd    = (const float*)d_in[3];
    const float* Wfuse = (const float*)d_in[4];
    float* out = (float*)d_out;

    unsigned short* WcombB = (unsigned short*)d_ws;        // 27*64*64*2   = 221184 B
    unsigned short* WoffR  = WcombB + 27 * 64 * 64;        // 9*64*64*2    =  73728 B
    unsigned short* xT     = WoffR + 9 * 64 * 64;          // 2*HW*64*2    = 16.78 MB

    prep_kernel<<<2624, 256, 0, stream>>>(x, xT, Wd, Wfuse, Woff, WcombB, WoffR);
    mspadc_main<<<2048, 256, 0, stream>>>(xT, WoffR, boff, WcombB, out);
}

// Round 14
// 285.796 us; speedup vs baseline: 1.0303x; 1.0227x over previous
//
#include <hip/hip_runtime.h>
#include <hip/hip_bf16.h>

#define HH 256
#define WW 256
#define HW (HH * WW)

typedef float f32x4 __attribute__((ext_vector_type(4)));
typedef float v2f __attribute__((ext_vector_type(2)));
typedef short bf16x8 __attribute__((ext_vector_type(8)));

__device__ __forceinline__ unsigned short f2bf(float f) {
    unsigned u = __builtin_bit_cast(unsigned, f);
    return (unsigned short)((u + 0x7FFFu + ((u >> 16) & 1u)) >> 16);
}
__device__ __forceinline__ v2f bfpair(unsigned u) {
    return (v2f){ __builtin_bit_cast(float, u << 16),
                  __builtin_bit_cast(float, u & 0xFFFF0000u) };
}
// RNE pack of two f32 -> packed bf16x2 (lo = first arg). Single v_cvt_pk_bf16_f32.
// (__hip_bfloat162 is not trivially copyable on this ROCm -> memcpy the bits.)
__device__ __forceinline__ unsigned pk_bf16(float lo, float hi) {
    __hip_bfloat162 h = __float22bfloat162_rn(make_float2(lo, hi));
    unsigned r;
    __builtin_memcpy(&r, &h, sizeof(r));
    return r;
}

// MERGED prep kernel (R13, verified): blocks [0,2048) = xT transpose,
// blocks [2048,2624) = weight prep. Bodies byte-identical to R12 versions.
__global__ void prep_kernel(const float* __restrict__ x, unsigned short* __restrict__ xT,
                            const float* __restrict__ Wd,
                            const float* __restrict__ Wfuse,
                            const float* __restrict__ Woff,
                            unsigned short* __restrict__ WcombB,
                            unsigned short* __restrict__ WoffR) {
    if (blockIdx.x < 2048) {
        // ---- xT transpose: x[b][c][h][w] fp32 -> xT[b][h][w][c] bf16 ----
        const int gid = blockIdx.x * 256 + threadIdx.x;       // 0..524287
        const int pix = gid >> 2;                             // 0..131071
        const int c16 = gid & 3;
        const float* xp = x + (size_t)(pix >> 16) * 64 * HW + (pix & 65535) + (size_t)(c16 * 16) * HW;
        unsigned short* op = xT + (size_t)pix * 64 + c16 * 16;
        unsigned q[8];
#pragma unroll
        for (int j = 0; j < 8; ++j) {
            float a = xp[(size_t)(2 * j) * HW];
            float b = xp[(size_t)(2 * j + 1) * HW];
            q[j] = pk_bf16(a, b);
        }
        *(uint4*)(op) = make_uint4(q[0], q[1], q[2], q[3]);
        *(uint4*)(op + 8) = make_uint4(q[4], q[5], q[6], q[7]);
    } else {
        // ---- weight prep ----
        //  WcombB[s][o][c] bf16 (s=i*9+t): sum_c2 Wfuse[o][i*64+c2] * Wd[i][c2][c][t]
        //  WoffR[t][n(64 pad)][c] bf16 from Woff[n][c][t]
        int idx = (blockIdx.x - 2048) * 256 + threadIdx.x;
        if (idx < 27 * 64 * 64) {
            int c = idx & 63, o = (idx >> 6) & 63, s = idx >> 12;
            int i = s / 9, t = s - i * 9;
            const float* wf = Wfuse + o * 192 + i * 64;
            const float* wd = Wd + ((size_t)(i * 64) * 64 + c) * 9 + t;
            float acc = 0.f;
            for (int c2 = 0; c2 < 64; ++c2)
                acc = fmaf(wf[c2], wd[(size_t)c2 * 576], acc);
            WcombB[idx] = f2bf(acc);          // (s*64+o)*64 + c
        } else {
            int j = idx - 27 * 64 * 64;
            if (j < 9 * 64 * 64) {
                int c = j & 63, n = (j >> 6) & 63, t = j >> 12;
                float v = (n < 54) ? Woff[(size_t)(n * 64 + c) * 9 + t] : 0.f;
                WoffR[j] = f2bf(v);           // (t*64+n)*64 + c
            }
        }
    }
}

// Block = 4 waves, one 64-pixel row segment. R13 structure. SINGLE delta this
// round: s_setprio(1)/(0) around consume's MFMA+load cluster (T5). Mechanism:
// within an iteration produce(s+1) [gather/VALU] and consume(s) [MFMA] have no
// barrier between them, so resident waves are at DIFFERENT phases — setprio
// lets MFMA-phase waves win issue arbitration over gather-stalled waves.
// Scheduler hint only: zero numerics/memory-semantics change, NOT a produce
// restructure (that class — R1/R3/R4/R8 — corrupts output and stays forbidden).
// Probed-null ledger: VALU halved (R7,-6us), occupancy 41->47% (R9,0), Sb bank
// pitch (R11,0), TA line grouping (R12,0), launch merge (R13,-2us total).
// Gathers are L2/L3-resident (FETCH ~10.9 MB/dispatch); stall = L2-hit latency.
__launch_bounds__(256, 5)
__global__ void mspadc_main(const unsigned short* __restrict__ xT,
                            const unsigned short* __restrict__ WoffR,
                            const float* __restrict__ boff,
                            const unsigned short* __restrict__ WcombB,
                            float* __restrict__ out) {
    __shared__ float offL[54 * 65];                          // [n<54][p] pitch 65
    __shared__ __align__(16) unsigned short Sb[2][64 * 70];  // [p][c] pitch 70

    const int tid = threadIdx.x, lane = tid & 63, wv = tid >> 6;
    const int l15 = lane & 15, lq = lane >> 4;

    const unsigned u = blockIdx.x;
    const int xcd = u & 7, v = u >> 3;                    // XCD-band swizzle
    const int row = xcd * 64 + (v >> 2);                  // 0..511
    const int b = row >> 8, h = row & 255;
    const int w0 = (v & 3) << 6;

    const unsigned short* xTb = xT + (size_t)b * HW * 64;

    f32x4 acc[4];
#pragma unroll
    for (int nt = 0; nt < 4; ++nt) acc[nt] = (f32x4){0.f, 0.f, 0.f, 0.f};

    // ---------------- Phase 1: offset conv GEMM ----------------
#pragma unroll
    for (int t = 0; t < 9; ++t) {
        const int hh = h + t / 3 - 1;
        const bool hv = (hh >= 0) && (hh < HH);
#pragma unroll
        for (int kk = 0; kk < 2; ++kk) {
            bf16x8 a = *(const bf16x8*)(WoffR + (size_t)((t * 64 + 16 * wv + l15) * 64 + kk * 32 + lq * 8));
#pragma unroll
            for (int nt = 0; nt < 4; ++nt) {
                const int ww = w0 + nt * 16 + l15 + (t % 3) - 1;
                bf16x8 bf_ = {0, 0, 0, 0, 0, 0, 0, 0};
                if (hv && ww >= 0 && ww < WW)
                    bf_ = *(const bf16x8*)(xTb + (size_t)(hh * WW + ww) * 64 + kk * 32 + lq * 8);
                acc[nt] = __builtin_amdgcn_mfma_f32_16x16x32_bf16(a, bf_, acc[nt], 0, 0, 0);
            }
        }
    }
#pragma unroll
    for (int r = 0; r < 4; ++r) {
        const int nch = 16 * wv + lq * 4 + r;
        if (nch < 54) {                      // rows >=54 are never read
            const float bo = boff[nch];
#pragma unroll
            for (int nt = 0; nt < 4; ++nt)
                offL[nch * 65 + nt * 16 + l15] = acc[nt][r] + bo;
        }
    }
    __syncthreads();

#pragma unroll
    for (int nt = 0; nt < 4; ++nt) acc[nt] = (f32x4){0.f, 0.f, 0.f, 0.f};

    // ---------------- Phase 2: gather + main GEMM ----------------
    const int c16 = tid & 3;       // channel group: [c16*8,+8) and [32+c16*8,+8)
    const int px  = tid >> 2;      // pixel 0..63 (one per thread)

    auto produce = [&](int s, int buf) {
        const int i = s / 9, t = s - i * 9;
        const int d = 1 << i;
        const int p = px;
        const float dy = offL[(i * 18 + 2 * t) * 65 + p];
        const float dx = offL[(i * 18 + 2 * t + 1) * 65 + p];
        const float ys = (float)(h + (t / 3 - 1) * d) + dy;
        const float xs = (float)(w0 + p + (t % 3 - 1) * d) + dx;
        const float y0f = floorf(ys), x0f = floorf(xs);
        const float wy1 = ys - y0f, wx1 = xs - x0f;
        const float wy0 = 1.f - wy1, wx0 = 1.f - wx1;
        const float vy0 = (y0f >= 0.f && y0f <= 255.f) ? 1.f : 0.f;
        const float vy1 = (y0f >= -1.f && y0f <= 254.f) ? 1.f : 0.f;
        const float vx0 = (x0f >= 0.f && x0f <= 255.f) ? 1.f : 0.f;
        const float vx1 = (x0f >= -1.f && x0f <= 254.f) ? 1.f : 0.f;
        const float c00 = wy0 * wx0 * vy0 * vx0;
        const float c01 = wy0 * wx1 * vy0 * vx1;
        const float c10 = wy1 * wx0 * vy1 * vx0;
        const float c11 = wy1 * wx1 * vy1 * vx1;
        const int y0 = (int)fminf(fmaxf(y0f, 0.f), 255.f);
        const int x0 = (int)fminf(fmaxf(x0f, 0.f), 255.f);
        const int oxs = (((int)fminf(fmaxf(x0f + 1.f, 0.f), 255.f)) - x0) * 64;
        const int oyW = (((int)fminf(fmaxf(y0f + 1.f, 0.f), 255.f)) - y0) * WW * 64;
        const unsigned short* pc = xTb + (size_t)(y0 * WW + x0) * 64 + c16 * 8;
        const uint4 u00a = *(const uint4*)(pc);            // line 0 of record
        const uint4 u00b = *(const uint4*)(pc + 32);       // line 1 (+64B)
        const uint4 u01a = *(const uint4*)(pc + oxs);
        const uint4 u01b = *(const uint4*)(pc + oxs + 32);
        const uint4 u10a = *(const uint4*)(pc + oyW);
        const uint4 u10b = *(const uint4*)(pc + oyW + 32);
        const uint4 u11a = *(const uint4*)(pc + oyW + oxs);
        const uint4 u11b = *(const uint4*)(pc + oyW + oxs + 32);
        const unsigned a00[8] = {u00a.x, u00a.y, u00a.z, u00a.w, u00b.x, u00b.y, u00b.z, u00b.w};
        const unsigned a01[8] = {u01a.x, u01a.y, u01a.z, u01a.w, u01b.x, u01b.y, u01b.z, u01b.w};
        const unsigned a10[8] = {u10a.x, u10a.y, u10a.z, u10a.w, u10b.x, u10b.y, u10b.z, u10b.w};
        const unsigned a11[8] = {u11a.x, u11a.y, u11a.z, u11a.w, u11b.x, u11b.y, u11b.z, u11b.w};
        const v2f c00v = {c00, c00}, c01v = {c01, c01};
        const v2f c10v = {c10, c10}, c11v = {c11, c11};
        unsigned q[8];
#pragma unroll
        for (int j = 0; j < 8; ++j) {
            v2f s2 = bfpair(a00[j]) * c00v;
            s2 = __builtin_elementwise_fma(bfpair(a01[j]), c01v, s2);
            s2 = __builtin_elementwise_fma(bfpair(a10[j]), c10v, s2);
            s2 = __builtin_elementwise_fma(bfpair(a11[j]), c11v, s2);
            q[j] = pk_bf16(s2.x, s2.y);
        }
        *(uint4*)(&Sb[buf][p * 70 + c16 * 8]) = make_uint4(q[0], q[1], q[2], q[3]);
        *(uint4*)(&Sb[buf][p * 70 + 32 + c16 * 8]) = make_uint4(q[4], q[5], q[6], q[7]);
    };

    auto consume = [&](int s, int buf) {
        __builtin_amdgcn_s_setprio(1);     // T5: favor MFMA-phase waves
#pragma unroll
        for (int kk = 0; kk < 2; ++kk) {
            bf16x8 a = *(const bf16x8*)(WcombB + (size_t)((s * 64 + 16 * wv + l15) * 64 + kk * 32 + lq * 8));
#pragma unroll
            for (int nt = 0; nt < 4; ++nt) {
                bf16x8 bb = *(const bf16x8*)(&Sb[buf][(nt * 16 + l15) * 70 + kk * 32 + lq * 8]);
                acc[nt] = __builtin_amdgcn_mfma_f32_16x16x32_bf16(a, bb, acc[nt], 0, 0, 0);
            }
        }
        __builtin_amdgcn_s_setprio(0);
    };

    produce(0, 0);
    __syncthreads();
    for (int s = 0; s < 27; ++s) {
        if (s < 26) produce(s + 1, (s + 1) & 1);
        consume(s, s & 1);
        __syncthreads();
    }

    // ---------------- Epilogue ----------------
    float* ob = out + (size_t)b * 64 * HW + h * WW + w0;
#pragma unroll
    for (int nt = 0; nt < 4; ++nt)
#pragma unroll
        for (int r = 0; r < 4; ++r) {
            const int o = 16 * wv + lq * 4 + r;
            ob[(size_t)o * HW + nt * 16 + l15] = acc[nt][r];
        }
}

extern "C" void kernel_launch(void* const* d_in, const int* in_sizes, int n_in,
                              void* d_out, int out_size, void* d_ws, size_t ws_size,
                              hipStream_t stream) {
    const float* x     = (const float*)d_in[0];
    const float* Woff  = (const float*)d_in[1];
    const float* boff  = (const float*)d_in[2];
    const float* Wd    = (const float*)d_in[3];
    const float* Wfuse = (const float*)d_in[4];
    float* out = (float*)d_out;

    unsigned short* WcombB = (unsigned short*)d_ws;        // 27*64*64*2   = 221184 B
    unsigned short* WoffR  = WcombB + 27 * 64 * 64;        // 9*64*64*2    =  73728 B
    unsigned short* xT     = WoffR + 9 * 64 * 64;          // 2*HW*64*2    = 16.78 MB

    prep_kernel<<<2624, 256, 0, stream>>>(x, xT, Wd, Wfuse, Woff, WcombB, WoffR);
    mspadc_main<<<2048, 256, 0, stream>>>(xT, WoffR, boff, WcombB, out);
}

// Round 15
// 285.646 us; speedup vs baseline: 1.0309x; 1.0005x over previous
//
#include <hip/hip_runtime.h>
#include <hip/hip_bf16.h>

#define HH 256
#define WW 256
#define HW (HH * WW)

typedef float f32x4 __attribute__((ext_vector_type(4)));
typedef float v2f __attribute__((ext_vector_type(2)));
typedef short bf16x8 __attribute__((ext_vector_type(8)));

__device__ __forceinline__ unsigned short f2bf(float f) {
    unsigned u = __builtin_bit_cast(unsigned, f);
    return (unsigned short)((u + 0x7FFFu + ((u >> 16) & 1u)) >> 16);
}
__device__ __forceinline__ v2f bfpair(unsigned u) {
    return (v2f){ __builtin_bit_cast(float, u << 16),
                  __builtin_bit_cast(float, u & 0xFFFF0000u) };
}
// RNE pack of two f32 -> packed bf16x2 (lo = first arg). Single v_cvt_pk_bf16_f32.
// (__hip_bfloat162 is not trivially copyable on this ROCm -> memcpy the bits.)
__device__ __forceinline__ unsigned pk_bf16(float lo, float hi) {
    __hip_bfloat162 h = __float22bfloat162_rn(make_float2(lo, hi));
    unsigned r;
    __builtin_memcpy(&r, &h, sizeof(r));
    return r;
}

// MERGED prep kernel. R15 delta: wprep blocks FIRST (blockIdx < 576), xt after.
// Previous order let xt's 8192 waves fill all slots, serializing wprep's 576
// latency-bound blocks (64-deep FMA chains, 36-lines/instr Wd gathers) into a
// near-serial tail at 2.25 blocks/CU. wprep-first co-schedules both from t=0:
// wprep's latency chains hide under xt's BW-bound phase. Bodies byte-identical.
__global__ void prep_kernel(const float* __restrict__ x, unsigned short* __restrict__ xT,
                            const float* __restrict__ Wd,
                            const float* __restrict__ Wfuse,
                            const float* __restrict__ Woff,
                            unsigned short* __restrict__ WcombB,
                            unsigned short* __restrict__ WoffR) {
    if (blockIdx.x < 576) {
        // ---- weight prep ----
        //  WcombB[s][o][c] bf16 (s=i*9+t): sum_c2 Wfuse[o][i*64+c2] * Wd[i][c2][c][t]
        //  WoffR[t][n(64 pad)][c] bf16 from Woff[n][c][t]
        int idx = blockIdx.x * 256 + threadIdx.x;
        if (idx < 27 * 64 * 64) {
            int c = idx & 63, o = (idx >> 6) & 63, s = idx >> 12;
            int i = s / 9, t = s - i * 9;
            const float* wf = Wfuse + o * 192 + i * 64;
            const float* wd = Wd + ((size_t)(i * 64) * 64 + c) * 9 + t;
            float acc = 0.f;
            for (int c2 = 0; c2 < 64; ++c2)
                acc = fmaf(wf[c2], wd[(size_t)c2 * 576], acc);
            WcombB[idx] = f2bf(acc);          // (s*64+o)*64 + c
        } else {
            int j = idx - 27 * 64 * 64;
            if (j < 9 * 64 * 64) {
                int c = j & 63, n = (j >> 6) & 63, t = j >> 12;
                float v = (n < 54) ? Woff[(size_t)(n * 64 + c) * 9 + t] : 0.f;
                WoffR[j] = f2bf(v);           // (t*64+n)*64 + c
            }
        }
    } else {
        // ---- xT transpose: x[b][c][h][w] fp32 -> xT[b][h][w][c] bf16 ----
        const int gid = (blockIdx.x - 576) * 256 + threadIdx.x;   // 0..524287
        const int pix = gid >> 2;                                 // 0..131071
        const int c16 = gid & 3;
        const float* xp = x + (size_t)(pix >> 16) * 64 * HW + (pix & 65535) + (size_t)(c16 * 16) * HW;
        unsigned short* op = xT + (size_t)pix * 64 + c16 * 16;
        unsigned q[8];
#pragma unroll
        for (int j = 0; j < 8; ++j) {
            float a = xp[(size_t)(2 * j) * HW];
            float b = xp[(size_t)(2 * j + 1) * HW];
            q[j] = pk_bf16(a, b);
        }
        *(uint4*)(op) = make_uint4(q[0], q[1], q[2], q[3]);
        *(uint4*)(op + 8) = make_uint4(q[4], q[5], q[6], q[7]);
    }
}

// Block = 4 waves, one 64-pixel row segment. R14 structure (consume setprio
// banked, -6us verified). SINGLE mspadc delta this round: extend the validated
// T5 hint to phase-1's MFMA cluster — resident blocks are lifecycle-staggered,
// so phase-1 MFMA waves compete with other blocks' gather/produce waves; give
// the MFMA cluster issue priority. Hint-only, zero numerics. REVERT if mspadc
// regresses (>215us).
// Probed ledger: VALU halved (R7,-6), occupancy (R9,0), Sb banks (R11,0),
// TA lines (R12,0), merge (R13,-2), consume setprio (R14,-6).
// Produce/consume restructures forbidden (R1/R3/R4/R8: 4/4 corrupt ~0.3).
__launch_bounds__(256, 5)
__global__ void mspadc_main(const unsigned short* __restrict__ xT,
                            const unsigned short* __restrict__ WoffR,
                            const float* __restrict__ boff,
                            const unsigned short* __restrict__ WcombB,
                            float* __restrict__ out) {
    __shared__ float offL[54 * 65];                          // [n<54][p] pitch 65
    __shared__ __align__(16) unsigned short Sb[2][64 * 70];  // [p][c] pitch 70

    const int tid = threadIdx.x, lane = tid & 63, wv = tid >> 6;
    const int l15 = lane & 15, lq = lane >> 4;

    const unsigned u = blockIdx.x;
    const int xcd = u & 7, v = u >> 3;                    // XCD-band swizzle
    const int row = xcd * 64 + (v >> 2);                  // 0..511
    const int b = row >> 8, h = row & 255;
    const int w0 = (v & 3) << 6;

    const unsigned short* xTb = xT + (size_t)b * HW * 64;

    f32x4 acc[4];
#pragma unroll
    for (int nt = 0; nt < 4; ++nt) acc[nt] = (f32x4){0.f, 0.f, 0.f, 0.f};

    // ---------------- Phase 1: offset conv GEMM ----------------
    __builtin_amdgcn_s_setprio(1);     // T5 extension: favor MFMA-phase waves
#pragma unroll
    for (int t = 0; t < 9; ++t) {
        const int hh = h + t / 3 - 1;
        const bool hv = (hh >= 0) && (hh < HH);
#pragma unroll
        for (int kk = 0; kk < 2; ++kk) {
            bf16x8 a = *(const bf16x8*)(WoffR + (size_t)((t * 64 + 16 * wv + l15) * 64 + kk * 32 + lq * 8));
#pragma unroll
            for (int nt = 0; nt < 4; ++nt) {
                const int ww = w0 + nt * 16 + l15 + (t % 3) - 1;
                bf16x8 bf_ = {0, 0, 0, 0, 0, 0, 0, 0};
                if (hv && ww >= 0 && ww < WW)
                    bf_ = *(const bf16x8*)(xTb + (size_t)(hh * WW + ww) * 64 + kk * 32 + lq * 8);
                acc[nt] = __builtin_amdgcn_mfma_f32_16x16x32_bf16(a, bf_, acc[nt], 0, 0, 0);
            }
        }
    }
    __builtin_amdgcn_s_setprio(0);
#pragma unroll
    for (int r = 0; r < 4; ++r) {
        const int nch = 16 * wv + lq * 4 + r;
        if (nch < 54) {                      // rows >=54 are never read
            const float bo = boff[nch];
#pragma unroll
            for (int nt = 0; nt < 4; ++nt)
                offL[nch * 65 + nt * 16 + l15] = acc[nt][r] + bo;
        }
    }
    __syncthreads();

#pragma unroll
    for (int nt = 0; nt < 4; ++nt) acc[nt] = (f32x4){0.f, 0.f, 0.f, 0.f};

    // ---------------- Phase 2: gather + main GEMM ----------------
    const int c16 = tid & 3;       // channel group: [c16*8,+8) and [32+c16*8,+8)
    const int px  = tid >> 2;      // pixel 0..63 (one per thread)

    auto produce = [&](int s, int buf) {
        const int i = s / 9, t = s - i * 9;
        const int d = 1 << i;
        const int p = px;
        const float dy = offL[(i * 18 + 2 * t) * 65 + p];
        const float dx = offL[(i * 18 + 2 * t + 1) * 65 + p];
        const float ys = (float)(h + (t / 3 - 1) * d) + dy;
        const float xs = (float)(w0 + p + (t % 3 - 1) * d) + dx;
        const float y0f = floorf(ys), x0f = floorf(xs);
        const float wy1 = ys - y0f, wx1 = xs - x0f;
        const float wy0 = 1.f - wy1, wx0 = 1.f - wx1;
        const float vy0 = (y0f >= 0.f && y0f <= 255.f) ? 1.f : 0.f;
        const float vy1 = (y0f >= -1.f && y0f <= 254.f) ? 1.f : 0.f;
        const float vx0 = (x0f >= 0.f && x0f <= 255.f) ? 1.f : 0.f;
        const float vx1 = (x0f >= -1.f && x0f <= 254.f) ? 1.f : 0.f;
        const float c00 = wy0 * wx0 * vy0 * vx0;
        const float c01 = wy0 * wx1 * vy0 * vx1;
        const float c10 = wy1 * wx0 * vy1 * vx0;
        const float c11 = wy1 * wx1 * vy1 * vx1;
        const int y0 = (int)fminf(fmaxf(y0f, 0.f), 255.f);
        const int x0 = (int)fminf(fmaxf(x0f, 0.f), 255.f);
        const int oxs = (((int)fminf(fmaxf(x0f + 1.f, 0.f), 255.f)) - x0) * 64;
        const int oyW = (((int)fminf(fmaxf(y0f + 1.f, 0.f), 255.f)) - y0) * WW * 64;
        const unsigned short* pc = xTb + (size_t)(y0 * WW + x0) * 64 + c16 * 8;
        const uint4 u00a = *(const uint4*)(pc);            // line 0 of record
        const uint4 u00b = *(const uint4*)(pc + 32);       // line 1 (+64B)
        const uint4 u01a = *(const uint4*)(pc + oxs);
        const uint4 u01b = *(const uint4*)(pc + oxs + 32);
        const uint4 u10a = *(const uint4*)(pc + oyW);
        const uint4 u10b = *(const uint4*)(pc + oyW + 32);
        const uint4 u11a = *(const uint4*)(pc + oyW + oxs);
        const uint4 u11b = *(const uint4*)(pc + oyW + oxs + 32);
        const unsigned a00[8] = {u00a.x, u00a.y, u00a.z, u00a.w, u00b.x, u00b.y, u00b.z, u00b.w};
        const unsigned a01[8] = {u01a.x, u01a.y, u01a.z, u01a.w, u01b.x, u01b.y, u01b.z, u01b.w};
        const unsigned a10[8] = {u10a.x, u10a.y, u10a.z, u10a.w, u10b.x, u10b.y, u10b.z, u10b.w};
        const unsigned a11[8] = {u11a.x, u11a.y, u11a.z, u11a.w, u11b.x, u11b.y, u11b.z, u11b.w};
        const v2f c00v = {c00, c00}, c01v = {c01, c01};
        const v2f c10v = {c10, c10}, c11v = {c11, c11};
        unsigned q[8];
#pragma unroll
        for (int j = 0; j < 8; ++j) {
            v2f s2 = bfpair(a00[j]) * c00v;
            s2 = __builtin_elementwise_fma(bfpair(a01[j]), c01v, s2);
            s2 = __builtin_elementwise_fma(bfpair(a10[j]), c10v, s2);
            s2 = __builtin_elementwise_fma(bfpair(a11[j]), c11v, s2);
            q[j] = pk_bf16(s2.x, s2.y);
        }
        *(uint4*)(&Sb[buf][p * 70 + c16 * 8]) = make_uint4(q[0], q[1], q[2], q[3]);
        *(uint4*)(&Sb[buf][p * 70 + 32 + c16 * 8]) = make_uint4(q[4], q[5], q[6], q[7]);
    };

    auto consume = [&](int s, int buf) {
        __builtin_amdgcn_s_setprio(1);     // T5 (R14, verified -6us)
#pragma unroll
        for (int kk = 0; kk < 2; ++kk) {
            bf16x8 a = *(const bf16x8*)(WcombB + (size_t)((s * 64 + 16 * wv + l15) * 64 + kk * 32 + lq * 8));
#pragma unroll
            for (int nt = 0; nt < 4; ++nt) {
                bf16x8 bb = *(const bf16x8*)(&Sb[buf][(nt * 16 + l15) * 70 + kk * 32 + lq * 8]);
                acc[nt] = __builtin_amdgcn_mfma_f32_16x16x32_bf16(a, bb, acc[nt], 0, 0, 0);
            }
        }
        __builtin_amdgcn_s_setprio(0);
    };

    produce(0, 0);
    __syncthreads();
    for (int s = 0; s < 27; ++s) {
        if (s < 26) produce(s + 1, (s + 1) & 1);
        consume(s, s & 1);
        __syncthreads();
    }

    // ---------------- Epilogue ----------------
    float* ob = out + (size_t)b * 64 * HW + h * WW + w0;
#pragma unroll
    for (int nt = 0; nt < 4; ++nt)
#pragma unroll
        for (int r = 0; r < 4; ++r) {
            const int o = 16 * wv + lq * 4 + r;
            ob[(size_t)o * HW + nt * 16 + l15] = acc[nt][r];
        }
}

extern "C" void kernel_launch(void* const* d_in, const int* in_sizes, int n_in,
                              void* d_out, int out_size, void* d_ws, size_t ws_size,
                              hipStream_t stream) {
    const float* x     = (const float*)d_in[0];
    const float* Woff  = (const float*)d_in[1];
    const float* boff  = (const float*)d_in[2];
    const float* Wd    = (const float*)d_in[3];
    const float* Wfuse = (const float*)d_in[4];
    float* out = (float*)d_out;

    unsigned short* WcombB = (unsigned short*)d_ws;        // 27*64*64*2   = 221184 B
    unsigned short* WoffR  = WcombB + 27 * 64 * 64;        // 9*64*64*2    =  73728 B
    unsigned short* xT     = WoffR + 9 * 64 * 64;          // 2*HW*64*2    = 16.78 MB

    prep_kernel<<<2624, 256, 0, stream>>>(x, xT, Wd, Wfuse, Woff, WcombB, WoffR);
    mspadc_main<<<2048, 256, 0, stream>>>(xT, WoffR, boff, WcombB, out);
}

// Round 16
// 284.584 us; speedup vs baseline: 1.0347x; 1.0037x over previous
//
#include <hip/hip_runtime.h>
#include <hip/hip_bf16.h>

#define HH 256
#define WW 256
#define HW (HH * WW)

typedef float f32x4 __attribute__((ext_vector_type(4)));
typedef float v2f __attribute__((ext_vector_type(2)));
typedef short bf16x8 __attribute__((ext_vector_type(8)));

__device__ __forceinline__ unsigned short f2bf(float f) {
    unsigned u = __builtin_bit_cast(unsigned, f);
    return (unsigned short)((u + 0x7FFFu + ((u >> 16) & 1u)) >> 16);
}
__device__ __forceinline__ v2f bfpair(unsigned u) {
    return (v2f){ __builtin_bit_cast(float, u << 16),
                  __builtin_bit_cast(float, u & 0xFFFF0000u) };
}
// RNE pack of two f32 -> packed bf16x2 (lo = first arg). Single v_cvt_pk_bf16_f32.
// (__hip_bfloat162 is not trivially copyable on this ROCm -> memcpy the bits.)
__device__ __forceinline__ unsigned pk_bf16(float lo, float hi) {
    __hip_bfloat162 h = __float22bfloat162_rn(make_float2(lo, hi));
    unsigned r;
    __builtin_memcpy(&r, &h, sizeof(r));
    return r;
}

// MERGED prep kernel. R16 delta: wprep's 64-deep serial load->fmaf chain split
// into 4 independent accumulator chains (c2%4) + full unroll. Each wd load is
// stride-2304B (own L2 line, ~250cy); single-chain = 64x250 = 16K cy/thread and
// wprep has only ~2 waves/SIMD of TLP -> chain latency was the last unprobed
// band candidate (xt regrid R11: null; merge R13: -2us; reorder R15: null).
// Reassociation changes WcombB by ~1e-6 rel (threshold 0.077) — safe.
__global__ void prep_kernel(const float* __restrict__ x, unsigned short* __restrict__ xT,
                            const float* __restrict__ Wd,
                            const float* __restrict__ Wfuse,
                            const float* __restrict__ Woff,
                            unsigned short* __restrict__ WcombB,
                            unsigned short* __restrict__ WoffR) {
    if (blockIdx.x < 576) {
        // ---- weight prep ----
        //  WcombB[s][o][c] bf16 (s=i*9+t): sum_c2 Wfuse[o][i*64+c2] * Wd[i][c2][c][t]
        //  WoffR[t][n(64 pad)][c] bf16 from Woff[n][c][t]
        int idx = blockIdx.x * 256 + threadIdx.x;
        if (idx < 27 * 64 * 64) {
            int c = idx & 63, o = (idx >> 6) & 63, s = idx >> 12;
            int i = s / 9, t = s - i * 9;
            const float* wf = Wfuse + o * 192 + i * 64;
            const float* wd = Wd + ((size_t)(i * 64) * 64 + c) * 9 + t;
            float a0 = 0.f, a1 = 0.f, a2 = 0.f, a3 = 0.f;
#pragma unroll
            for (int c2 = 0; c2 < 64; c2 += 4) {
                a0 = fmaf(wf[c2],     wd[(size_t)(c2)     * 576], a0);
                a1 = fmaf(wf[c2 + 1], wd[(size_t)(c2 + 1) * 576], a1);
                a2 = fmaf(wf[c2 + 2], wd[(size_t)(c2 + 2) * 576], a2);
                a3 = fmaf(wf[c2 + 3], wd[(size_t)(c2 + 3) * 576], a3);
            }
            WcombB[idx] = f2bf((a0 + a1) + (a2 + a3));   // (s*64+o)*64 + c
        } else {
            int j = idx - 27 * 64 * 64;
            if (j < 9 * 64 * 64) {
                int c = j & 63, n = (j >> 6) & 63, t = j >> 12;
                float v = (n < 54) ? Woff[(size_t)(n * 64 + c) * 9 + t] : 0.f;
                WoffR[j] = f2bf(v);           // (t*64+n)*64 + c
            }
        }
    } else {
        // ---- xT transpose: x[b][c][h][w] fp32 -> xT[b][h][w][c] bf16 ----
        const int gid = (blockIdx.x - 576) * 256 + threadIdx.x;   // 0..524287
        const int pix = gid >> 2;                                 // 0..131071
        const int c16 = gid & 3;
        const float* xp = x + (size_t)(pix >> 16) * 64 * HW + (pix & 65535) + (size_t)(c16 * 16) * HW;
        unsigned short* op = xT + (size_t)pix * 64 + c16 * 16;
        unsigned q[8];
#pragma unroll
        for (int j = 0; j < 8; ++j) {
            float a = xp[(size_t)(2 * j) * HW];
            float b = xp[(size_t)(2 * j + 1) * HW];
            q[j] = pk_bf16(a, b);
        }
        *(uint4*)(op) = make_uint4(q[0], q[1], q[2], q[3]);
        *(uint4*)(op + 8) = make_uint4(q[4], q[5], q[6], q[7]);
    }
}

// Block = 4 waves, one 64-pixel row segment. BYTE-IDENTICAL to verified R15
// (212.2-212.7us, absmax 0.015625). At its structural floor: ~58% of cycles are
// correlated latency waits (L2-hit gather chains behind per-slice barriers);
// occupancy/banks/TA/priority levers all probed null or banked.
// Produce/consume restructures forbidden (R1/R3/R4/R8: 4/4 corrupt ~0.3).
// Banked: VALU halving (R7,-6), setprio consume (R14,-6), LDS diet (R9),
// pack intrinsic (R5,-5).
__launch_bounds__(256, 5)
__global__ void mspadc_main(const unsigned short* __restrict__ xT,
                            const unsigned short* __restrict__ WoffR,
                            const float* __restrict__ boff,
                            const unsigned short* __restrict__ WcombB,
                            float* __restrict__ out) {
    __shared__ float offL[54 * 65];                          // [n<54][p] pitch 65
    __shared__ __align__(16) unsigned short Sb[2][64 * 70];  // [p][c] pitch 70

    const int tid = threadIdx.x, lane = tid & 63, wv = tid >> 6;
    const int l15 = lane & 15, lq = lane >> 4;

    const unsigned u = blockIdx.x;
    const int xcd = u & 7, v = u >> 3;                    // XCD-band swizzle
    const int row = xcd * 64 + (v >> 2);                  // 0..511
    const int b = row >> 8, h = row & 255;
    const int w0 = (v & 3) << 6;

    const unsigned short* xTb = xT + (size_t)b * HW * 64;

    f32x4 acc[4];
#pragma unroll
    for (int nt = 0; nt < 4; ++nt) acc[nt] = (f32x4){0.f, 0.f, 0.f, 0.f};

    // ---------------- Phase 1: offset conv GEMM ----------------
    __builtin_amdgcn_s_setprio(1);     // neutral-verified (R15), kept
#pragma unroll
    for (int t = 0; t < 9; ++t) {
        const int hh = h + t / 3 - 1;
        const bool hv = (hh >= 0) && (hh < HH);
#pragma unroll
        for (int kk = 0; kk < 2; ++kk) {
            bf16x8 a = *(const bf16x8*)(WoffR + (size_t)((t * 64 + 16 * wv + l15) * 64 + kk * 32 + lq * 8));
#pragma unroll
            for (int nt = 0; nt < 4; ++nt) {
                const int ww = w0 + nt * 16 + l15 + (t % 3) - 1;
                bf16x8 bf_ = {0, 0, 0, 0, 0, 0, 0, 0};
                if (hv && ww >= 0 && ww < WW)
                    bf_ = *(const bf16x8*)(xTb + (size_t)(hh * WW + ww) * 64 + kk * 32 + lq * 8);
                acc[nt] = __builtin_amdgcn_mfma_f32_16x16x32_bf16(a, bf_, acc[nt], 0, 0, 0);
            }
        }
    }
    __builtin_amdgcn_s_setprio(0);
#pragma unroll
    for (int r = 0; r < 4; ++r) {
        const int nch = 16 * wv + lq * 4 + r;
        if (nch < 54) {                      // rows >=54 are never read
            const float bo = boff[nch];
#pragma unroll
            for (int nt = 0; nt < 4; ++nt)
                offL[nch * 65 + nt * 16 + l15] = acc[nt][r] + bo;
        }
    }
    __syncthreads();

#pragma unroll
    for (int nt = 0; nt < 4; ++nt) acc[nt] = (f32x4){0.f, 0.f, 0.f, 0.f};

    // ---------------- Phase 2: gather + main GEMM ----------------
    const int c16 = tid & 3;       // channel group: [c16*8,+8) and [32+c16*8,+8)
    const int px  = tid >> 2;      // pixel 0..63 (one per thread)

    auto produce = [&](int s, int buf) {
        const int i = s / 9, t = s - i * 9;
        const int d = 1 << i;
        const int p = px;
        const float dy = offL[(i * 18 + 2 * t) * 65 + p];
        const float dx = offL[(i * 18 + 2 * t + 1) * 65 + p];
        const float ys = (float)(h + (t / 3 - 1) * d) + dy;
        const float xs = (float)(w0 + p + (t % 3 - 1) * d) + dx;
        const float y0f = floorf(ys), x0f = floorf(xs);
        const float wy1 = ys - y0f, wx1 = xs - x0f;
        const float wy0 = 1.f - wy1, wx0 = 1.f - wx1;
        const float vy0 = (y0f >= 0.f && y0f <= 255.f) ? 1.f : 0.f;
        const float vy1 = (y0f >= -1.f && y0f <= 254.f) ? 1.f : 0.f;
        const float vx0 = (x0f >= 0.f && x0f <= 255.f) ? 1.f : 0.f;
        const float vx1 = (x0f >= -1.f && x0f <= 254.f) ? 1.f : 0.f;
        const float c00 = wy0 * wx0 * vy0 * vx0;
        const float c01 = wy0 * wx1 * vy0 * vx1;
        const float c10 = wy1 * wx0 * vy1 * vx0;
        const float c11 = wy1 * wx1 * vy1 * vx1;
        const int y0 = (int)fminf(fmaxf(y0f, 0.f), 255.f);
        const int x0 = (int)fminf(fmaxf(x0f, 0.f), 255.f);
        const int oxs = (((int)fminf(fmaxf(x0f + 1.f, 0.f), 255.f)) - x0) * 64;
        const int oyW = (((int)fminf(fmaxf(y0f + 1.f, 0.f), 255.f)) - y0) * WW * 64;
        const unsigned short* pc = xTb + (size_t)(y0 * WW + x0) * 64 + c16 * 8;
        const uint4 u00a = *(const uint4*)(pc);            // line 0 of record
        const uint4 u00b = *(const uint4*)(pc + 32);       // line 1 (+64B)
        const uint4 u01a = *(const uint4*)(pc + oxs);
        const uint4 u01b = *(const uint4*)(pc + oxs + 32);
        const uint4 u10a = *(const uint4*)(pc + oyW);
        const uint4 u10b = *(const uint4*)(pc + oyW + 32);
        const uint4 u11a = *(const uint4*)(pc + oyW + oxs);
        const uint4 u11b = *(const uint4*)(pc + oyW + oxs + 32);
        const unsigned a00[8] = {u00a.x, u00a.y, u00a.z, u00a.w, u00b.x, u00b.y, u00b.z, u00b.w};
        const unsigned a01[8] = {u01a.x, u01a.y, u01a.z, u01a.w, u01b.x, u01b.y, u01b.z, u01b.w};
        const unsigned a10[8] = {u10a.x, u10a.y, u10a.z, u10a.w, u10b.x, u10b.y, u10b.z, u10b.w};
        const unsigned a11[8] = {u11a.x, u11a.y, u11a.z, u11a.w, u11b.x, u11b.y, u11b.z, u11b.w};
        const v2f c00v = {c00, c00}, c01v = {c01, c01};
        const v2f c10v = {c10, c10}, c11v = {c11, c11};
        unsigned q[8];
#pragma unroll
        for (int j = 0; j < 8; ++j) {
            v2f s2 = bfpair(a00[j]) * c00v;
            s2 = __builtin_elementwise_fma(bfpair(a01[j]), c01v, s2);
            s2 = __builtin_elementwise_fma(bfpair(a10[j]), c10v, s2);
            s2 = __builtin_elementwise_fma(bfpair(a11[j]), c11v, s2);
            q[j] = pk_bf16(s2.x, s2.y);
        }
        *(uint4*)(&Sb[buf][p * 70 + c16 * 8]) = make_uint4(q[0], q[1], q[2], q[3]);
        *(uint4*)(&Sb[buf][p * 70 + 32 + c16 * 8]) = make_uint4(q[4], q[5], q[6], q[7]);
    };

    auto consume = [&](int s, int buf) {
        __builtin_amdgcn_s_setprio(1);     // T5 (R14, verified -6us)
#pragma unroll
        for (int kk = 0; kk < 2; ++kk) {
            bf16x8 a = *(const bf16x8*)(WcombB + (size_t)((s * 64 + 16 * wv + l15) * 64 + kk * 32 + lq * 8));
#pragma unroll
            for (int nt = 0; nt < 4; ++nt) {
                bf16x8 bb = *(const bf16x8*)(&Sb[buf][(nt * 16 + l15) * 70 + kk * 32 + lq * 8]);
                acc[nt] = __builtin_amdgcn_mfma_f32_16x16x32_bf16(a, bb, acc[nt], 0, 0, 0);
            }
        }
        __builtin_amdgcn_s_setprio(0);
    };

    produce(0, 0);
    __syncthreads();
    for (int s = 0; s < 27; ++s) {
        if (s < 26) produce(s + 1, (s + 1) & 1);
        consume(s, s & 1);
        __syncthreads();
    }

    // ---------------- Epilogue ----------------
    float* ob = out + (size_t)b * 64 * HW + h * WW + w0;
#pragma unroll
    for (int nt = 0; nt < 4; ++nt)
#pragma unroll
        for (int r = 0; r < 4; ++r) {
            const int o = 16 * wv + lq * 4 + r;
            ob[(size_t)o * HW + nt * 16 + l15] = acc[nt][r];
        }
}

extern "C" void kernel_launch(void* const* d_in, const int* in_sizes, int n_in,
                              void* d_out, int out_size, void* d_ws, size_t ws_size,
                              hipStream_t stream) {
    const float* x     = (const float*)d_in[0];
    const float* Woff  = (const float*)d_in[1];
    const float* boff  = (const float*)d_in[2];
    const float* Wd    = (const float*)d_in[3];
    const float* Wfuse = (const float*)d_in[4];
    float* out = (float*)d_out;

    unsigned short* WcombB = (unsigned short*)d_ws;        // 27*64*64*2   = 221184 B
    unsigned short* WoffR  = WcombB + 27 * 64 * 64;        // 9*64*64*2    =  73728 B
    unsigned short* xT     = WoffR + 9 * 64 * 64;          // 2*HW*64*2    = 16.78 MB

    prep_kernel<<<2624, 256, 0, stream>>>(x, xT, Wd, Wfuse, Woff, WcombB, WoffR);
    mspadc_main<<<2048, 256, 0, stream>>>(xT, WoffR, boff, WcombB, out);
}